// Round 21
// baseline (78.694 us; speedup 1.0000x reference)
//
#include <hip/hip_runtime.h>

#define H_ 16
#define D_ 128

typedef __attribute__((ext_vector_type(4))) float f32x4;
typedef __attribute__((ext_vector_type(8))) short bf8_t;   // 8 bf16 (4 VGPRs)
typedef __attribute__((ext_vector_type(4))) unsigned int u32x4;

__device__ __forceinline__ unsigned cvt_pk(float a, float b) {
  unsigned r;
  asm("v_cvt_pk_bf16_f32 %0, %1, %2" : "=v"(r) : "v"(a), "v"(b));
  return r;  // low 16 = bf16(a), high 16 = bf16(b)
}

__device__ __forceinline__ float exp2a(float x) {
  float r;
  asm("v_exp_f32 %0, %1" : "=v"(r) : "v"(x));  // 2^x
  return r;
}

__device__ __forceinline__ bf8_t cvt8(const f32x4 a, const f32x4 b) {
  u32x4 r;
  r[0] = cvt_pk(a[0], a[1]); r[1] = cvt_pk(a[2], a[3]);
  r[2] = cvt_pk(b[0], b[1]); r[3] = cvt_pk(b[2], b[3]);
  return __builtin_bit_cast(bf8_t, r);
}

// ---- one-time fused pass: K -> bf16 chunk-swizzled, V -> bf16 transposed+slot-permuted.
__global__ __launch_bounds__(128)
void conv_kv(const float* __restrict__ K, const float* __restrict__ V,
             const int* __restrict__ cuk, short* __restrict__ Kbf,
             short* __restrict__ Vt, int B, int T) {
  const int J0 = blockIdx.x * 8;
  const int h  = blockIdx.y;
  int b = 0;
  while (b + 1 < B && J0 >= cuk[b + 1]) ++b;
  const int k0 = cuk[b];

  {
    const int g = J0 + (threadIdx.x >> 4);
    const int c = threadIdx.x & 15;
    const int sub = c ^ ((g - k0) & 7);
    const float* src = K + ((size_t)g * H_ + h) * D_ + sub * 8;
    *(bf8_t*)(Kbf + ((size_t)g * H_ + h) * D_ + c * 8) =
        cvt8(*(const f32x4*)src, *(const f32x4*)(src + 4));
  }
  {
    const int d  = threadIdx.x;
    const int j0 = J0 - k0;
    const int base = k0 + (j0 >> 6) * 64 + 32 * ((j0 >> 5) & 1) + 4 * ((j0 >> 3) & 3);
    float v[8];
    #pragma unroll
    for (int s = 0; s < 8; ++s)
      v[s] = V[((size_t)(base + 16 * (s >> 2) + (s & 3)) * H_ + h) * D_ + d];
    u32x4 w;
    w[0] = cvt_pk(v[0], v[1]); w[1] = cvt_pk(v[2], v[3]);
    w[2] = cvt_pk(v[4], v[5]); w[3] = cvt_pk(v[6], v[7]);
    *(u32x4*)(Vt + ((size_t)h * D_ + d) * T + J0) = w;
  }
}

__global__ __launch_bounds__(256, 2)
void fa_main(const float* __restrict__ Q, const short* __restrict__ Kbf,
             const short* __restrict__ Vt, const int* __restrict__ cuq,
             const int* __restrict__ cuk, float* __restrict__ O, int B, int T) {
  // SINGLE-buffered 128-key tiles:
  // K [128 key][16 chunk x 16B] (swizzle in content), V [128 d][16 chunk x 16B]
  __shared__ __align__(16) short k_lds[128 * 128];     // 32 KB
  __shared__ __align__(16) short v_lds[128 * 128];     // 32 KB -> 64 KB total

  // ---- placement-aware slot -> (b, qt, h) decode (R18, unchanged)
  const int slot = blockIdx.x;
  int bmax = 0, nmax = 0, tot = 0;
  for (int bb = 0; bb < B; ++bb) {
    const int nk = (cuk[bb + 1] - cuk[bb] + 63) >> 6;
    if (nk > nmax) { nmax = nk; bmax = bb; }
    tot += ((cuq[bb + 1] - cuq[bb] + 127) >> 7) * 16;
  }
  if (slot >= tot) return;
  const int L = ((cuq[bmax + 1] - cuq[bmax] + 127) >> 7) * 16;
  const int halfS = (tot - L) >> 1;

  int b = -1, item = 0;
  if (slot >= halfS && slot < halfS + L) {
    b = bmax; item = slot - halfS;
  } else {
    int sidx = (slot < halfS) ? slot : slot - L;
    for (int bb = 0; bb < B; ++bb) {
      if (bb == bmax) continue;
      const int it = ((cuq[bb + 1] - cuq[bb] + 127) >> 7) * 16;
      if (sidx < it) { b = bb; item = sidx; break; }
      sidx -= it;
    }
    if (b < 0) return;
  }
  const int qt = item >> 4;
  const int h  = item & 15;

  const int q0   = cuq[b];
  const int lenq = cuq[b + 1] - q0;
  const int k0   = cuk[b];
  const int lenk = cuk[b + 1] - k0;
  const int nkt2 = (lenk + 127) >> 7;   // 128-key tiles

  const int tid  = threadIdx.x;
  const int wave = tid >> 6;
  const int lane = tid & 63;
  const int lo   = lane & 15;
  const int gp   = lane >> 4;

  const int qrow_base = qt * 128 + wave * 32;

  // ---- Q B-fragments (col = lo = q, k-slot = d)
  bf8_t qf[2][4];
  #pragma unroll
  for (int s2 = 0; s2 < 2; ++s2) {
    const int qr = qrow_base + s2 * 16 + lo;
    const int qg = q0 + (qr < lenq ? qr : lenq - 1);
    const float* qp = Q + ((size_t)qg * H_ + h) * D_;
    #pragma unroll
    for (int db = 0; db < 4; ++db) {
      const f32x4 a = *reinterpret_cast<const f32x4*>(qp + db * 32 + gp * 8);
      const f32x4 c = *reinterpret_cast<const f32x4*>(qp + db * 32 + gp * 8 + 4);
      qf[s2][db] = cvt8(a, c);
    }
  }

  f32x4 acc[2][8];
  #pragma unroll
  for (int s2 = 0; s2 < 2; ++s2)
    #pragma unroll
    for (int i = 0; i < 8; ++i) acc[s2][i] = f32x4{0.f, 0.f, 0.f, 0.f};
  f32x4 acc_l[2] = {f32x4{0.f, 0.f, 0.f, 0.f}, f32x4{0.f, 0.f, 0.f, 0.f}};

  bf8_t onesf;
  #pragma unroll
  for (int i = 0; i < 8; ++i) onesf[i] = (short)0x3F80;  // 1.0 bf16

  const int skey = tid >> 4;          // K: rows skey + 16i, chunk = ssub
  const int ssub = tid & 15;
  const int vd5  = tid >> 3;          // V: d = dq*32 + vd5, phys chunk = vcp (in half)
  const int vcp  = tid & 7;
  const int vclog = vcp ^ (vd5 & 7);  // logical chunk at this slot
  const short* KbH = Kbf + h * D_ + ssub * 8;
  const short* VtH = Vt + ((size_t)h * D_) * T;

  // p = exp2(y*P'(y^2) - ce), y = S*(cz*ce), clamp |y| <= 0.68*ce
  const float cy  = 0.12752749f;
  const float ce  = 28.853901f;
  const float ycl = 19.620652f;
  const float c3p = -4.0037686e-4f;
  const float c4p = 1.9236228e-7f;

  // ---- register prefetch for a full 128-key tile (16 x 16B per thread)
  u32x4 krb[8], vrb[8];
  auto issue_loads = [&](int kb) {
    #pragma unroll
    for (int i = 0; i < 8; ++i) {
      const int kk = kb + skey + 16 * i;
      const size_t gk = (size_t)(k0 + (kk < lenk ? kk : lenk - 1));
      krb[i] = *(const u32x4*)(KbH + gk * (H_ * D_));
    }
    #pragma unroll
    for (int i = 0; i < 8; ++i) {
      const int half = i >> 2;
      const int d = (i & 3) * 32 + vd5;
      vrb[i] = *(const u32x4*)(VtH + (size_t)d * T + (k0 + kb + half * 64 + vclog * 8));
    }
  };
  auto write_tile = [&]() {
    char* kb2 = (char*)k_lds;
    char* vb2 = (char*)v_lds;
    #pragma unroll
    for (int i = 0; i < 8; ++i)
      *(u32x4*)(kb2 + (skey + 16 * i) * 256 + ssub * 16) = krb[i];
    #pragma unroll
    for (int i = 0; i < 8; ++i) {
      const int half = i >> 2;
      const int d = (i & 3) * 32 + vd5;
      *(u32x4*)(vb2 + d * 256 + (half * 8 + vcp) * 16) = vrb[i];
    }
  };

  issue_loads(0);
  write_tile();
  __syncthreads();

  for (int kt = 0; kt < nkt2; ++kt) {
    const int kb = kt * 128;

    if (kt + 1 < nkt2) issue_loads(kb + 128);
    __builtin_amdgcn_sched_barrier(0);

    const bool fullTile = (kb + 128 <= lenk);
    u32x4 pf[2][4];

    // ---- process the 128-key tile in two 64-key halves: QK -> SM -> pf
    #pragma unroll
    for (int half = 0; half < 2; ++half) {
      f32x4 s[2][4];
      #pragma unroll
      for (int s2 = 0; s2 < 2; ++s2)
        #pragma unroll
        for (int kq = 0; kq < 4; ++kq) s[s2][kq] = f32x4{0.f, 0.f, 0.f, 0.f};
      __builtin_amdgcn_s_setprio(1);
      #pragma unroll
      for (int db = 0; db < 4; ++db) {
        #pragma unroll
        for (int kq = 0; kq < 4; ++kq) {
          const bf8_t kf = *(const bf8_t*)((char*)k_lds +
              (half * 64 + kq * 16 + lo) * 256 + (((4 * db + gp) ^ (lo & 7)) << 4));
          s[0][kq] = __builtin_amdgcn_mfma_f32_16x16x32_bf16(kf, qf[0][db], s[0][kq], 0, 0, 0);
          s[1][kq] = __builtin_amdgcn_mfma_f32_16x16x32_bf16(kf, qf[1][db], s[1][kq], 0, 0, 0);
        }
      }
      __builtin_amdgcn_s_setprio(0);

      if (fullTile) {
        #pragma unroll
        for (int s2 = 0; s2 < 2; ++s2) {
          #pragma unroll
          for (int kq = 0; kq < 4; ++kq) {
            #pragma unroll
            for (int r = 0; r < 4; ++r) {
              float y = s[s2][kq][r] * cy;
              y = __builtin_amdgcn_fmed3f(y, -ycl, ycl);
              const float u = y * y;
              const float pol = fmaf(u, fmaf(u, c4p, c3p), 1.0f);
              s[s2][kq][r] = exp2a(fmaf(y, pol, -ce));
            }
          }
        }
      } else {
        #pragma unroll
        for (int s2 = 0; s2 < 2; ++s2) {
          #pragma unroll
          for (int kq = 0; kq < 4; ++kq) {
            const int keyb = kb + half * 64 + 16 * kq + 4 * gp;
            #pragma unroll
            for (int r = 0; r < 4; ++r) {
              float y = s[s2][kq][r] * cy;
              y = __builtin_amdgcn_fmed3f(y, -ycl, ycl);
              const float u = y * y;
              const float pol = fmaf(u, fmaf(u, c4p, c3p), 1.0f);
              float p = exp2a(fmaf(y, pol, -ce));
              s[s2][kq][r] = (keyb + r < lenk) ? p : 0.0f;
            }
          }
        }
      }

      // pf[s2][half*2 + ksl]: slot i holds key 64*half + 32*ksl + 4gp + (i&3) + 16(i>>2)
      #pragma unroll
      for (int s2 = 0; s2 < 2; ++s2) {
        #pragma unroll
        for (int ksl = 0; ksl < 2; ++ksl) {
          pf[s2][half * 2 + ksl][0] = cvt_pk(s[s2][2 * ksl][0], s[s2][2 * ksl][1]);
          pf[s2][half * 2 + ksl][1] = cvt_pk(s[s2][2 * ksl][2], s[s2][2 * ksl][3]);
          pf[s2][half * 2 + ksl][2] = cvt_pk(s[s2][2 * ksl + 1][0], s[s2][2 * ksl + 1][1]);
          pf[s2][half * 2 + ksl][3] = cvt_pk(s[s2][2 * ksl + 1][2], s[s2][2 * ksl + 1][3]);
        }
      }
    }

    // ---- PV over 4 x 32-key groups (+ l via ones-column MFMA)
    __builtin_amdgcn_s_setprio(1);
    #pragma unroll
    for (int ks = 0; ks < 4; ++ks) {
      acc_l[0] = __builtin_amdgcn_mfma_f32_16x16x32_bf16(
          __builtin_bit_cast(bf8_t, pf[0][ks]), onesf, acc_l[0], 0, 0, 0);
      acc_l[1] = __builtin_amdgcn_mfma_f32_16x16x32_bf16(
          __builtin_bit_cast(bf8_t, pf[1][ks]), onesf, acc_l[1], 0, 0, 0);
      const int half = ks >> 1;
      #pragma unroll
      for (int nt = 0; nt < 8; ++nt) {
        const int d = nt * 16 + lo;
        const bf8_t vf = *(const bf8_t*)((char*)v_lds + d * 256 +
            ((half * 8 + ((((ks & 1) << 2) + gp) ^ (lo & 7))) << 4));
        acc[0][nt] = __builtin_amdgcn_mfma_f32_16x16x32_bf16(
            __builtin_bit_cast(bf8_t, pf[0][ks]), vf, acc[0][nt], 0, 0, 0);
        acc[1][nt] = __builtin_amdgcn_mfma_f32_16x16x32_bf16(
            __builtin_bit_cast(bf8_t, pf[1][ks]), vf, acc[1][nt], 0, 0, 0);
      }
    }
    __builtin_amdgcn_s_setprio(0);

    __syncthreads();                        // all reads of tile kt complete
    if (kt + 1 < nkt2) {
      write_tile();                         // regs (landed under compute) -> LDS
      __syncthreads();                      // tile kt+1 visible
    }
  }

  // ---- epilogue: acc_l rows align with acc rows -> per-lane 1/l, no shuffles
  #pragma unroll
  for (int s2 = 0; s2 < 2; ++s2) {
    #pragma unroll
    for (int r = 0; r < 4; ++r) {
      const float inv_l = 1.0f / acc_l[s2][r];
      const int qr = qrow_base + s2 * 16 + 4 * gp + r;
      if (qr < lenq) {
        float* op = O + ((size_t)(q0 + qr) * H_ + h) * D_;
        #pragma unroll
        for (int nt = 0; nt < 8; ++nt)
          op[nt * 16 + lo] = acc[s2][nt][r] * inv_l;
      }
    }
  }
}

extern "C" void kernel_launch(void* const* d_in, const int* in_sizes, int n_in,
                              void* d_out, int out_size, void* d_ws, size_t ws_size,
                              hipStream_t stream) {
  const float* Q  = (const float*)d_in[0];
  const float* K  = (const float*)d_in[1];
  const float* V  = (const float*)d_in[2];
  const int* cuq  = (const int*)d_in[3];
  const int* cuk  = (const int*)d_in[4];
  float* out      = (float*)d_out;
  const int B = in_sizes[3] - 1;
  const int T = in_sizes[0] / (H_ * D_);

  short* Kbf = (short*)d_ws;
  short* Vt  = Kbf + (size_t)T * H_ * D_;

  conv_kv<<<dim3(T / 8, H_), 128, 0, stream>>>(K, V, cuk, Kbf, Vt, B, T);
  const int maxItems = 16 * (T / 128 + B);
  fa_main<<<maxItems, 256, 0, stream>>>(Q, Kbf, Vt, cuq, cuk, out, B, T);
}

// Round 22
// 61.491 us; speedup vs baseline: 1.2798x; 1.2798x over previous
//
#include <hip/hip_runtime.h>

#define H_ 16
#define D_ 128

typedef __attribute__((ext_vector_type(4))) float f32x4;
typedef __attribute__((ext_vector_type(8))) short bf8_t;   // 8 bf16 (4 VGPRs)
typedef __attribute__((ext_vector_type(4))) unsigned int u32x4;

__device__ __forceinline__ unsigned cvt_pk(float a, float b) {
  unsigned r;
  asm("v_cvt_pk_bf16_f32 %0, %1, %2" : "=v"(r) : "v"(a), "v"(b));
  return r;  // low 16 = bf16(a), high 16 = bf16(b)
}

__device__ __forceinline__ float exp2a(float x) {
  float r;
  asm("v_exp_f32 %0, %1" : "=v"(r) : "v"(x));  // 2^x
  return r;
}

__device__ __forceinline__ bf8_t cvt8(const f32x4 a, const f32x4 b) {
  u32x4 r;
  r[0] = cvt_pk(a[0], a[1]); r[1] = cvt_pk(a[2], a[3]);
  r[2] = cvt_pk(b[0], b[1]); r[3] = cvt_pk(b[2], b[3]);
  return __builtin_bit_cast(bf8_t, r);
}

// ---- one-time fused pass: K -> bf16 chunk-swizzled, V -> bf16 transposed+slot-permuted.
__global__ __launch_bounds__(128)
void conv_kv(const float* __restrict__ K, const float* __restrict__ V,
             const int* __restrict__ cuk, short* __restrict__ Kbf,
             short* __restrict__ Vt, int B, int T) {
  const int J0 = blockIdx.x * 8;
  const int h  = blockIdx.y;
  int b = 0;
  while (b + 1 < B && J0 >= cuk[b + 1]) ++b;
  const int k0 = cuk[b];

  {
    const int g = J0 + (threadIdx.x >> 4);
    const int c = threadIdx.x & 15;
    const int sub = c ^ ((g - k0) & 7);
    const float* src = K + ((size_t)g * H_ + h) * D_ + sub * 8;
    *(bf8_t*)(Kbf + ((size_t)g * H_ + h) * D_ + c * 8) =
        cvt8(*(const f32x4*)src, *(const f32x4*)(src + 4));
  }
  {
    const int d  = threadIdx.x;
    const int j0 = J0 - k0;
    const int base = k0 + (j0 >> 6) * 64 + 32 * ((j0 >> 5) & 1) + 4 * ((j0 >> 3) & 3);
    float v[8];
    #pragma unroll
    for (int s = 0; s < 8; ++s)
      v[s] = V[((size_t)(base + 16 * (s >> 2) + (s & 3)) * H_ + h) * D_ + d];
    u32x4 w;
    w[0] = cvt_pk(v[0], v[1]); w[1] = cvt_pk(v[2], v[3]);
    w[2] = cvt_pk(v[4], v[5]); w[3] = cvt_pk(v[6], v[7]);
    *(u32x4*)(Vt + ((size_t)h * D_ + d) * T + J0) = w;
  }
}

__global__ __launch_bounds__(256, 2)
void fa_main(const float* __restrict__ Q, const short* __restrict__ Kbf,
             const short* __restrict__ Vt, const int* __restrict__ cuq,
             const int* __restrict__ cuk, float* __restrict__ O, int B, int T) {
  __shared__ __align__(16) short k_lds[2][64 * 128];   // 32 KB
  __shared__ __align__(16) short v_lds[2][64 * 128];   // 32 KB -> 64 KB total

  // ---- placement-aware slot -> (b, qt, h) decode (R18)
  const int slot = blockIdx.x;
  int bmax = 0, nmax = 0, tot = 0;
  for (int bb = 0; bb < B; ++bb) {
    const int nk = (cuk[bb + 1] - cuk[bb] + 63) >> 6;
    if (nk > nmax) { nmax = nk; bmax = bb; }
    tot += ((cuq[bb + 1] - cuq[bb] + 127) >> 7) * 16;
  }
  if (slot >= tot) return;
  const int L = ((cuq[bmax + 1] - cuq[bmax] + 127) >> 7) * 16;
  const int halfS = (tot - L) >> 1;

  int b = -1, item = 0;
  if (slot >= halfS && slot < halfS + L) {
    b = bmax; item = slot - halfS;
  } else {
    int sidx = (slot < halfS) ? slot : slot - L;
    for (int bb = 0; bb < B; ++bb) {
      if (bb == bmax) continue;
      const int it = ((cuq[bb + 1] - cuq[bb] + 127) >> 7) * 16;
      if (sidx < it) { b = bb; item = sidx; break; }
      sidx -= it;
    }
    if (b < 0) return;
  }
  const int qt = item >> 4;
  const int h  = item & 15;

  const int q0   = cuq[b];
  const int lenq = cuq[b + 1] - q0;
  const int k0   = cuk[b];
  const int lenk = cuk[b + 1] - k0;
  const int nkt  = (lenk + 63) >> 6;

  const int tid  = threadIdx.x;
  const int wave = tid >> 6;
  const int lane = tid & 63;
  const int lo   = lane & 15;
  const int gp   = lane >> 4;

  const int qrow_base = qt * 128 + wave * 32;

  // ---- Q B-fragments (col = lo = q, k-slot = d)
  bf8_t qf[2][4];
  #pragma unroll
  for (int s2 = 0; s2 < 2; ++s2) {
    const int qr = qrow_base + s2 * 16 + lo;
    const int qg = q0 + (qr < lenq ? qr : lenq - 1);
    const float* qp = Q + ((size_t)qg * H_ + h) * D_;
    #pragma unroll
    for (int db = 0; db < 4; ++db) {
      const f32x4 a = *reinterpret_cast<const f32x4*>(qp + db * 32 + gp * 8);
      const f32x4 c = *reinterpret_cast<const f32x4*>(qp + db * 32 + gp * 8 + 4);
      qf[s2][db] = cvt8(a, c);
    }
  }

  f32x4 acc[2][8];
  #pragma unroll
  for (int s2 = 0; s2 < 2; ++s2)
    #pragma unroll
    for (int i = 0; i < 8; ++i) acc[s2][i] = f32x4{0.f, 0.f, 0.f, 0.f};
  // l accumulated by MFMA with an all-ones B operand; rows align with acc rows.
  f32x4 acc_l[2] = {f32x4{0.f, 0.f, 0.f, 0.f}, f32x4{0.f, 0.f, 0.f, 0.f}};

  bf8_t onesf;
  #pragma unroll
  for (int i = 0; i < 8; ++i) onesf[i] = (short)0x3F80;  // 1.0 bf16

  const int skey = tid >> 4;
  const int ssub = tid & 15;
  const int vd5  = tid >> 3;
  const int vcp  = tid & 7;
  const int vclog = vcp ^ (vd5 & 7);
  const short* KbH = Kbf + h * D_ + ssub * 8;
  const short* VtH = Vt + ((size_t)h * D_) * T;

  // p = exp2(y*P'(y^2) - ce), y = S*(cz*ce), clamp |y| <= 0.68*ce
  const float cy  = 0.12752749f;     // cz * ce
  const float ce  = 28.853901f;      // 20 * log2(e)
  const float ycl = 19.620652f;      // 0.68 * ce
  const float c3p = -4.0037686e-4f;  // -1/(3*ce^2)
  const float c4p = 1.9236228e-7f;   // 2/(15*ce^4)

  u32x4 krb[4], vrb[4];
  auto issue_loads = [&](int kb) {
    #pragma unroll
    for (int i = 0; i < 4; ++i) {
      const int kk = kb + skey + 16 * i;
      const size_t gk = (size_t)(k0 + (kk < lenk ? kk : lenk - 1));
      krb[i] = *(const u32x4*)(KbH + gk * (H_ * D_));
    }
    #pragma unroll
    for (int i = 0; i < 4; ++i) {
      const int d = i * 32 + vd5;
      vrb[i] = *(const u32x4*)(VtH + (size_t)d * T + (k0 + kb + vclog * 8));
    }
  };
  auto write_tile = [&](int buf) {
    char* kb2 = (char*)k_lds[buf];
    char* vb2 = (char*)v_lds[buf];
    #pragma unroll
    for (int i = 0; i < 4; ++i)
      *(u32x4*)(kb2 + (skey + 16 * i) * 256 + ssub * 16) = krb[i];
    #pragma unroll
    for (int i = 0; i < 4; ++i)
      *(u32x4*)(vb2 + (i * 32 + vd5) * 128 + vcp * 16) = vrb[i];
  };

  issue_loads(0);
  write_tile(0);
  __syncthreads();

  for (int kt = 0; kt < nkt; ++kt) {
    const int kb = kt * 64;
    char* kbase = (char*)k_lds[kt & 1];
    char* vtb   = (char*)v_lds[kt & 1];

    if (kt + 1 < nkt) issue_loads(kb + 64);
    __builtin_amdgcn_sched_barrier(0);

    // ---- swapped QK^T: lane (lo,gp) holds S[key=16kq+4gp+r][q=lo]
    f32x4 s[2][4];
    #pragma unroll
    for (int s2 = 0; s2 < 2; ++s2)
      #pragma unroll
      for (int kq = 0; kq < 4; ++kq) s[s2][kq] = f32x4{0.f, 0.f, 0.f, 0.f};
    __builtin_amdgcn_s_setprio(1);
    #pragma unroll
    for (int db = 0; db < 4; ++db) {
      #pragma unroll
      for (int kq = 0; kq < 4; ++kq) {
        const bf8_t kf = *(const bf8_t*)(kbase + (kq * 16 + lo) * 256 +
                                         (((4 * db + gp) ^ (lo & 7)) << 4));
        s[0][kq] = __builtin_amdgcn_mfma_f32_16x16x32_bf16(kf, qf[0][db], s[0][kq], 0, 0, 0);
        s[1][kq] = __builtin_amdgcn_mfma_f32_16x16x32_bf16(kf, qf[1][db], s[1][kq], 0, 0, 0);
      }
    }
    __builtin_amdgcn_s_setprio(0);

    // ---- softcap+softmax: p = exp2(y*P'(y^2) - ce); mask only on partial tiles
    const bool fullTile = (kb + 64 <= lenk);
    if (fullTile) {
      #pragma unroll
      for (int s2 = 0; s2 < 2; ++s2) {
        #pragma unroll
        for (int kq = 0; kq < 4; ++kq) {
          #pragma unroll
          for (int r = 0; r < 4; ++r) {
            float y = s[s2][kq][r] * cy;
            y = __builtin_amdgcn_fmed3f(y, -ycl, ycl);
            const float u = y * y;
            const float pol = fmaf(u, fmaf(u, c4p, c3p), 1.0f);
            s[s2][kq][r] = exp2a(fmaf(y, pol, -ce));
          }
        }
      }
    } else {
      #pragma unroll
      for (int s2 = 0; s2 < 2; ++s2) {
        #pragma unroll
        for (int kq = 0; kq < 4; ++kq) {
          const int keyb = kb + 16 * kq + 4 * gp;
          #pragma unroll
          for (int r = 0; r < 4; ++r) {
            float y = s[s2][kq][r] * cy;
            y = __builtin_amdgcn_fmed3f(y, -ycl, ycl);
            const float u = y * y;
            const float pol = fmaf(u, fmaf(u, c4p, c3p), 1.0f);
            float p = exp2a(fmaf(y, pol, -ce));
            s[s2][kq][r] = (keyb + r < lenk) ? p : 0.0f;
          }
        }
      }
    }

    // ---- P -> A-fragments (slot i: key 32ks+4gp+(i&3)+16(i>>2))
    u32x4 pf[2][2];
    #pragma unroll
    for (int s2 = 0; s2 < 2; ++s2) {
      #pragma unroll
      for (int ks = 0; ks < 2; ++ks) {
        pf[s2][ks][0] = cvt_pk(s[s2][2 * ks][0], s[s2][2 * ks][1]);
        pf[s2][ks][1] = cvt_pk(s[s2][2 * ks][2], s[s2][2 * ks][3]);
        pf[s2][ks][2] = cvt_pk(s[s2][2 * ks + 1][0], s[s2][2 * ks + 1][1]);
        pf[s2][ks][3] = cvt_pk(s[s2][2 * ks + 1][2], s[s2][2 * ks + 1][3]);
      }
    }

    // ---- stage tile kt+1 now; ds_writes retire under PV (target buffer was
    // last read in iter kt-1; every wave passed that iteration's barrier)
    if (kt + 1 < nkt) write_tile((kt + 1) & 1);

    // ---- PV (+ l via ones-column MFMA)
    __builtin_amdgcn_s_setprio(1);
    #pragma unroll
    for (int ks = 0; ks < 2; ++ks) {
      acc_l[0] = __builtin_amdgcn_mfma_f32_16x16x32_bf16(
          __builtin_bit_cast(bf8_t, pf[0][ks]), onesf, acc_l[0], 0, 0, 0);
      acc_l[1] = __builtin_amdgcn_mfma_f32_16x16x32_bf16(
          __builtin_bit_cast(bf8_t, pf[1][ks]), onesf, acc_l[1], 0, 0, 0);
      #pragma unroll
      for (int nt = 0; nt < 8; ++nt) {
        const int d = nt * 16 + lo;
        const bf8_t vf = *(const bf8_t*)(
            vtb + d * 128 + ((((ks << 2) + gp) ^ (lo & 7)) << 4));
        acc[0][nt] = __builtin_amdgcn_mfma_f32_16x16x32_bf16(
            __builtin_bit_cast(bf8_t, pf[0][ks]), vf, acc[0][nt], 0, 0, 0);
        acc[1][nt] = __builtin_amdgcn_mfma_f32_16x16x32_bf16(
            __builtin_bit_cast(bf8_t, pf[1][ks]), vf, acc[1][nt], 0, 0, 0);
      }
    }
    __builtin_amdgcn_s_setprio(0);

    __syncthreads();
  }

  // ---- epilogue: acc_l rows align with acc rows -> per-lane 1/l, no shuffles
  #pragma unroll
  for (int s2 = 0; s2 < 2; ++s2) {
    #pragma unroll
    for (int r = 0; r < 4; ++r) {
      const float inv_l = 1.0f / acc_l[s2][r];
      const int qr = qrow_base + s2 * 16 + 4 * gp + r;
      if (qr < lenq) {
        float* op = O + ((size_t)(q0 + qr) * H_ + h) * D_;
        #pragma unroll
        for (int nt = 0; nt < 8; ++nt)
          op[nt * 16 + lo] = acc[s2][nt][r] * inv_l;
      }
    }
  }
}

extern "C" void kernel_launch(void* const* d_in, const int* in_sizes, int n_in,
                              void* d_out, int out_size, void* d_ws, size_t ws_size,
                              hipStream_t stream) {
  const float* Q  = (const float*)d_in[0];
  const float* K  = (const float*)d_in[1];
  const float* V  = (const float*)d_in[2];
  const int* cuq  = (const int*)d_in[3];
  const int* cuk  = (const int*)d_in[4];
  float* out      = (float*)d_out;
  const int B = in_sizes[3] - 1;
  const int T = in_sizes[0] / (H_ * D_);

  short* Kbf = (short*)d_ws;
  short* Vt  = Kbf + (size_t)T * H_ * D_;

  conv_kv<<<dim3(T / 8, H_), 128, 0, stream>>>(K, V, cuk, Kbf, Vt, B, T);
  const int maxItems = 16 * (T / 128 + B);
  fa_main<<<maxItems, 256, 0, stream>>>(Q, Kbf, Vt, cuq, cuk, out, B, T);
}